// Round 7
// baseline (769.226 us; speedup 1.0000x reference)
//
#include <hip/hip_runtime.h>

// RepetHead: 4 layers of (3x3 offset conv -> DCNv1 deform conv -> ReLU)
// B=4, C=256, H=W=64, K=9 taps.
// Round 7: deform K-loop has NO LDS staging and NO barriers. Each lane
// gathers its own 4 bilinear corners and builds its MFMA A-fragment in
// registers (A[m=lane&15][c=quad*8+j] == exactly what the lane computes).
// Waves free-run -> VALU combine and MFMA overlap across waves instead of
// alternating in barrier lockstep (r6: VALUBusy 40%, MfmaUtil 16%, 44%
// bubbles). hi/lo split uses v_cvt_pk_bf16_f32 when available.
//
// ws layout (floats):
//   offs :   294,912
//   wph  : 1,179,648  (2,359,296 ushort, deform B frag-packed, bf16-hi)
//   owph :   147,456  (  294,912 ushort, offset-conv B frag-packed)
//   xTA  : 2,097,152  (4,194,304 ushort, plane ping)
//   xTB  : 2,097,152  (4,194,304 ushort, plane pong)
// total 5,816,320 floats = 23.3 MB

#define HW 4096

typedef __attribute__((ext_vector_type(8))) __bf16 bf16x8;
typedef __attribute__((ext_vector_type(2))) __bf16 bf16x2;
typedef __attribute__((ext_vector_type(4))) float f32x4;
typedef __attribute__((ext_vector_type(8))) unsigned short u16x8;

__device__ inline unsigned int f2bf_bits(float f) {
  unsigned int u = __float_as_uint(f);
  return (u + 0x7fffu + ((u >> 16) & 1u)) >> 16;   // RNE to bf16
}
__device__ inline float bf_hi_f(unsigned short h) {
  return __uint_as_float(((unsigned int)h) << 16);
}

// split two fp32 into packed bf16 hi words + packed bf16 lo (residual) words
__device__ inline void split2(float v0, float v1,
                              unsigned int& hw, unsigned int& lw) {
#if __has_builtin(__builtin_amdgcn_cvt_pk_bf16_f32)
  bf16x2 h2 = __builtin_amdgcn_cvt_pk_bf16_f32(v0, v1);
  hw = __builtin_bit_cast(unsigned int, h2);
  const float r0 = v0 - __uint_as_float(hw << 16);
  const float r1 = v1 - __uint_as_float(hw & 0xffff0000u);
  bf16x2 l2 = __builtin_amdgcn_cvt_pk_bf16_f32(r0, r1);
  lw = __builtin_bit_cast(unsigned int, l2);
#else
  const unsigned int h0 = f2bf_bits(v0), h1 = f2bf_bits(v1);
  hw = h0 | (h1 << 16);
  const float r0 = v0 - __uint_as_float(h0 << 16);
  const float r1 = v1 - __uint_as_float(h1 << 16);
  lw = f2bf_bits(r0) | (f2bf_bits(r1) << 16);
#endif
}

// ---------------------------------------------------------------------------
// w[r][o][c][ky][kx] -> frag-packed wph[r][q=72][nt=16][lane=64][j=8] (bf16-hi)
// n = nt*16+(lane&15); kk = q*32+(lane>>4)*8+j; c = kk&255; k = kk>>8.
__global__ __launch_bounds__(256) void wpack_kernel(
    const float* __restrict__ w, unsigned short* __restrict__ wph) {
  const int f = blockIdx.x * 256 + threadIdx.x;   // < 2,359,296
  const int j  = f & 7;
  const int l  = (f >> 3) & 63;
  const int nt = (f >> 9) & 15;
  const int q  = (f >> 13) % 72;
  const int r  = f / 589824;
  const int n  = nt * 16 + (l & 15);
  const int kk = q * 32 + ((l >> 4) << 3) + j;
  const int c  = kk & 255, k = kk >> 8;
  wph[f] = (unsigned short)f2bf_bits(w[((r * 256 + n) * 256 + c) * 9 + k]);
}

// offw[r][18][256][3][3] -> owph[r][q=72][nt=2][lane=64][j=8] (n>=18 -> 0)
__global__ __launch_bounds__(256) void offwpack_kernel(
    const float* __restrict__ offw, unsigned short* __restrict__ owph) {
  const int f = blockIdx.x * 256 + threadIdx.x;   // < 294,912
  const int j  = f & 7;
  const int l  = (f >> 3) & 63;
  const int nt = (f >> 9) & 1;
  const int q  = (f >> 10) % 72;
  const int r  = f / 73728;
  const int n  = nt * 16 + (l & 15);
  const int kk = q * 32 + ((l >> 4) << 3) + j;
  const int c  = kk & 255, k = kk >> 8;
  const float v = (n < 18) ? offw[((r * 18 + n) * 256 + c) * 9 + k] : 0.f;
  owph[f] = (unsigned short)f2bf_bits(v);
}

// ---------------------------------------------------------------------------
// x [4][256][4096] fp32 -> xT [4][4096][256] bf16-hi (transpose + cast)
__global__ __launch_bounds__(256) void xpose_kernel(
    const float* __restrict__ x, unsigned short* __restrict__ xh) {
  const int p0 = blockIdx.x * 64;     // pos tile
  const int c0 = blockIdx.y * 64;     // channel tile
  const int b  = blockIdx.z;
  __shared__ float sT[64][65];
  const int t = threadIdx.x;
  const int pj = t & 63, ci0 = (t >> 6) * 16;
  const float* __restrict__ xb = x + ((size_t)(b * 256 + c0)) * HW + p0;
#pragma unroll
  for (int u = 0; u < 16; ++u)
    sT[ci0 + u][pj] = xb[(size_t)(ci0 + u) * HW + pj];
  __syncthreads();
  const int pr = t >> 2, cs = (t & 3) * 16;
  u16x8 va, vb;
#pragma unroll
  for (int u = 0; u < 8; ++u) va[u] = (unsigned short)f2bf_bits(sT[cs + u][pr]);
#pragma unroll
  for (int u = 0; u < 8; ++u) vb[u] = (unsigned short)f2bf_bits(sT[cs + 8 + u][pr]);
  const size_t o = ((size_t)b * HW + p0 + pr) * 256 + c0 + cs;
  *(u16x8*)(xh + o) = va;
  *(u16x8*)(xh + o + 8) = vb;
}

// ---------------------------------------------------------------------------
// Offset conv, zero-LDS MFMA (r4-proven). block = 32m x 32n, 4 waves.
__global__ __launch_bounds__(256) void offconv_mfma(
    const unsigned short* __restrict__ xh,
    const unsigned short* __restrict__ owh,
    const float* __restrict__ bias, float* __restrict__ offs) {
  const int gid = blockIdx.x;                 // 0..511
  const int b = (gid & 7) >> 1;
  const int idx = ((gid >> 3) << 1) | (gid & 1);   // 0..127
  const int h = idx >> 1, w0 = (idx & 1) << 5;
  const int t = threadIdx.x, lane = t & 63, wv = t >> 6;
  const int frow = lane & 15, fgrp = lane >> 4;
  const int mt = wv & 1, nt = wv >> 1;
  const int m = w0 + mt * 16 + frow;          // w coordinate of A row

  f32x4 acc = {0.f, 0.f, 0.f, 0.f};
  const u16x8 z8 = {};
  const size_t xb = (size_t)b * HW;

  for (int k = 0; k < 9; ++k) {
    const int ky = k / 3 - 1, kx = k % 3 - 1;
    if ((unsigned)(h + ky) >= 64u) continue;  // block-uniform: tap row is 0
    const bool vpx = (unsigned)(m + kx) < 64u;
    const int cpx = (m + kx) < 0 ? 0 : ((m + kx) > 63 ? 63 : (m + kx));
    const size_t abase = (xb + (size_t)((h + ky) * 64 + cpx)) * 256 + fgrp * 8;
#pragma unroll
    for (int cc = 0; cc < 8; ++cc) {
      const int q = k * 8 + cc;
      u16x8 ahr = *(const u16x8*)(xh + abase + cc * 32);
      if (!vpx) ahr = z8;
      const u16x8 bhr = ((const u16x8*)owh)[(q * 2 + nt) * 64 + lane];
      const bf16x8 ah = __builtin_bit_cast(bf16x8, ahr);
      const bf16x8 bh = __builtin_bit_cast(bf16x8, bhr);
      acc = __builtin_amdgcn_mfma_f32_16x16x32_bf16(ah, bh, acc, 0, 0, 0);
    }
  }
  const int oc = nt * 16 + frow;              // C/D: col = lane&15 -> n
  if (oc < 18) {
    const float bv = bias[oc];
    const int wbase = w0 + mt * 16 + fgrp * 4;  // C/D: row = (lane>>4)*4 + r
    float* __restrict__ op = offs + (size_t)(b * 18 + oc) * HW + h * 64 + wbase;
#pragma unroll
    for (int r = 0; r < 4; ++r) op[r] = acc[r] + bv;
  }
}

// ---------------------------------------------------------------------------
// Fused bilinear-sample + bf16 MFMA GEMM + ReLU. Register-resident A frags,
// no barriers in the K-loop. Block: M=64 x N=128, 4 waves = 2mw x 2nw;
// per wave 2 m-tiles x 4 n-tiles x 2 products (a_hi, a_lo) * b_hi.
__global__ __launch_bounds__(256) void deform_mfma(
    const unsigned short* __restrict__ xh,   // [4][4096][256] bf16-hi plane
    const float* __restrict__ offs,          // [4][18][4096]
    const unsigned short* __restrict__ wph,  // [72][16][64][8] this layer
    unsigned short* __restrict__ yth,        // next plane (layers 0-2)
    float* __restrict__ outf) {              // fp32 NCHW out (layer 3)
  const int gid = blockIdx.x;                  // 0..511
  const int b = (gid & 7) >> 1;                // 2 XCDs per batch image
  const int rh = ((gid >> 3) << 1) | (gid & 1);   // 0..127
  const int h = rh >> 1, nh = rh & 1;
  const int t = threadIdx.x, lane = t & 63, wv = t >> 6;
  const int mw = wv & 1, nw = wv >> 1;
  const int frow = lane & 15, quad = lane >> 4;

  __shared__ __align__(16) unsigned char s_mem[18432];
  float4* s_cw = (float4*)s_mem;               // [9][64] corner weights
  int4*   s_ci = (int4*)(s_mem + 9216);        // [9][64] corner row indices

  // phase 0: per (k, m) bilinear setup, m = w coordinate (full row)
  for (int i = t; i < 576; i += 256) {
    const int k = i >> 6, m = i & 63;
    const int ky = k / 3 - 1, kx = k % 3 - 1;
    const int pos = h * 64 + m;
    const float dy = offs[(b * 18 + 2 * k) * HW + pos];
    const float dx = offs[(b * 18 + 2 * k + 1) * HW + pos];
    const float py = (float)(h + ky) + dy;
    const float px = (float)(m + kx) + dx;
    const float y0f = floorf(py), x0f = floorf(px);
    const float wy = py - y0f, wx = px - x0f;
    const int y0 = (int)y0f, x0 = (int)x0f;
    float cw[4]; int ci[4];
#pragma unroll
    for (int j = 0; j < 4; ++j) {
      const int yi = y0 + (j >> 1), xi = x0 + (j & 1);
      const bool v = (yi >= 0) && (yi < 64) && (xi >= 0) && (xi < 64);
      const float wgt = ((j >> 1) ? wy : 1.f - wy) * ((j & 1) ? wx : 1.f - wx);
      cw[j] = v ? wgt : 0.f;
      const int yc = yi < 0 ? 0 : (yi > 63 ? 63 : yi);
      const int xc = xi < 0 ? 0 : (xi > 63 ? 63 : xi);
      ci[j] = yc * 64 + xc;
    }
    s_cw[k * 64 + m] = (float4){cw[0], cw[1], cw[2], cw[3]};
    s_ci[k * 64 + m] = (int4){ci[0], ci[1], ci[2], ci[3]};
  }
  __syncthreads();

  f32x4 acc[2][4];
#pragma unroll
  for (int mt = 0; mt < 2; ++mt)
#pragma unroll
    for (int nt = 0; nt < 4; ++nt) acc[mt][nt] = (f32x4){0.f, 0.f, 0.f, 0.f};

  const unsigned short* __restrict__ xbh = xh + (size_t)b * HW * 256;
  const u16x8* __restrict__ wp = (const u16x8*)wph;
  const int bfo = nh * 8 + nw * 4;             // B frag n-offset
  const int q8 = quad * 8;                     // this lane's channel sub-slot
  const int bm = mw * 32 + frow;               // mt=0 A row (m coordinate)

#pragma unroll 1
  for (int k = 0; k < 9; ++k) {
    // per-tap corner params for this lane's two m rows (LDS, read-only)
    const float4 cw0 = s_cw[k * 64 + bm];
    const float4 cw1 = s_cw[k * 64 + bm + 16];
    const int4   ci0 = s_ci[k * 64 + bm];
    const int4   ci1 = s_ci[k * 64 + bm + 16];
    // per-tap corner base pointers (chunk adds immediate cc*64B)
    const unsigned short* p00 = xbh + (size_t)ci0.x * 256 + q8;
    const unsigned short* p01 = xbh + (size_t)ci0.y * 256 + q8;
    const unsigned short* p02 = xbh + (size_t)ci0.z * 256 + q8;
    const unsigned short* p03 = xbh + (size_t)ci0.w * 256 + q8;
    const unsigned short* p10 = xbh + (size_t)ci1.x * 256 + q8;
    const unsigned short* p11 = xbh + (size_t)ci1.y * 256 + q8;
    const unsigned short* p12 = xbh + (size_t)ci1.z * 256 + q8;
    const unsigned short* p13 = xbh + (size_t)ci1.w * 256 + q8;
    const u16x8* wq = wp + ((size_t)(k * 8) * 16 + bfo) * 64 + lane;

#pragma unroll
    for (int cc = 0; cc < 8; ++cc) {
      // corner gathers (each lane: its own rows, its own 8-channel slice)
      const u16x8 g00 = *(const u16x8*)(p00 + cc * 32);
      const u16x8 g01 = *(const u16x8*)(p01 + cc * 32);
      const u16x8 g02 = *(const u16x8*)(p02 + cc * 32);
      const u16x8 g03 = *(const u16x8*)(p03 + cc * 32);
      const u16x8 g10 = *(const u16x8*)(p10 + cc * 32);
      const u16x8 g11 = *(const u16x8*)(p11 + cc * 32);
      const u16x8 g12 = *(const u16x8*)(p12 + cc * 32);
      const u16x8 g13 = *(const u16x8*)(p13 + cc * 32);
      // B frags
      const u16x8 b0 = wq[cc * 1024];
      const u16x8 b1 = wq[cc * 1024 + 64];
      const u16x8 b2 = wq[cc * 1024 + 128];
      const u16x8 b3 = wq[cc * 1024 + 192];
      // fp32 bilinear combine (per lane = its own A-frag elements)
      float v0[8], v1[8];
#pragma unroll
      for (int u = 0; u < 8; ++u) {
        float s = cw0.x * bf_hi_f(g00[u]);
        s = fmaf(cw0.y, bf_hi_f(g01[u]), s);
        s = fmaf(cw0.z, bf_hi_f(g02[u]), s);
        v0[u] = fmaf(cw0.w, bf_hi_f(g03[u]), s);
        float r = cw1.x * bf_hi_f(g10[u]);
        r = fmaf(cw1.y, bf_hi_f(g11[u]), r);
        r = fmaf(cw1.z, bf_hi_f(g12[u]), r);
        v1[u] = fmaf(cw1.w, bf_hi_f(g13[u]), r);
      }
      // hi/lo split straight into MFMA A operands
      uint4 h0w, l0w, h1w, l1w;
      split2(v0[0], v0[1], h0w.x, l0w.x);
      split2(v0[2], v0[3], h0w.y, l0w.y);
      split2(v0[4], v0[5], h0w.z, l0w.z);
      split2(v0[6], v0[7], h0w.w, l0w.w);
      split2(v1[0], v1[1], h1w.x, l1w.x);
      split2(v1[2], v1[3], h1w.y, l1w.y);
      split2(v1[4], v1[5], h1w.z, l1w.z);
      split2(v1[6], v1[7], h1w.w, l1w.w);
      const bf16x8 ah0 = __builtin_bit_cast(bf16x8, h0w);
      const bf16x8 al0 = __builtin_bit_cast(bf16x8, l0w);
      const bf16x8 ah1 = __builtin_bit_cast(bf16x8, h1w);
      const bf16x8 al1 = __builtin_bit_cast(bf16x8, l1w);
      const bf16x8 bv0 = __builtin_bit_cast(bf16x8, b0);
      const bf16x8 bv1 = __builtin_bit_cast(bf16x8, b1);
      const bf16x8 bv2 = __builtin_bit_cast(bf16x8, b2);
      const bf16x8 bv3 = __builtin_bit_cast(bf16x8, b3);
      acc[0][0] = __builtin_amdgcn_mfma_f32_16x16x32_bf16(ah0, bv0, acc[0][0], 0, 0, 0);
      acc[0][0] = __builtin_amdgcn_mfma_f32_16x16x32_bf16(al0, bv0, acc[0][0], 0, 0, 0);
      acc[1][0] = __builtin_amdgcn_mfma_f32_16x16x32_bf16(ah1, bv0, acc[1][0], 0, 0, 0);
      acc[1][0] = __builtin_amdgcn_mfma_f32_16x16x32_bf16(al1, bv0, acc[1][0], 0, 0, 0);
      acc[0][1] = __builtin_amdgcn_mfma_f32_16x16x32_bf16(ah0, bv1, acc[0][1], 0, 0, 0);
      acc[0][1] = __builtin_amdgcn_mfma_f32_16x16x32_bf16(al0, bv1, acc[0][1], 0, 0, 0);
      acc[1][1] = __builtin_amdgcn_mfma_f32_16x16x32_bf16(ah1, bv1, acc[1][1], 0, 0, 0);
      acc[1][1] = __builtin_amdgcn_mfma_f32_16x16x32_bf16(al1, bv1, acc[1][1], 0, 0, 0);
      acc[0][2] = __builtin_amdgcn_mfma_f32_16x16x32_bf16(ah0, bv2, acc[0][2], 0, 0, 0);
      acc[0][2] = __builtin_amdgcn_mfma_f32_16x16x32_bf16(al0, bv2, acc[0][2], 0, 0, 0);
      acc[1][2] = __builtin_amdgcn_mfma_f32_16x16x32_bf16(ah1, bv2, acc[1][2], 0, 0, 0);
      acc[1][2] = __builtin_amdgcn_mfma_f32_16x16x32_bf16(al1, bv2, acc[1][2], 0, 0, 0);
      acc[0][3] = __builtin_amdgcn_mfma_f32_16x16x32_bf16(ah0, bv3, acc[0][3], 0, 0, 0);
      acc[0][3] = __builtin_amdgcn_mfma_f32_16x16x32_bf16(al0, bv3, acc[0][3], 0, 0, 0);
      acc[1][3] = __builtin_amdgcn_mfma_f32_16x16x32_bf16(ah1, bv3, acc[1][3], 0, 0, 0);
      acc[1][3] = __builtin_amdgcn_mfma_f32_16x16x32_bf16(al1, bv3, acc[1][3], 0, 0, 0);
    }
  }

  if (outf) {
    // final layer: ReLU + direct fp32 NCHW scatter (float4 per tile-row)
#pragma unroll
    for (int mt = 0; mt < 2; ++mt)
#pragma unroll
      for (int nt = 0; nt < 4; ++nt) {
        const int n = nh * 128 + (nw * 4 + nt) * 16 + frow;
        const int pos = h * 64 + (mw * 2 + mt) * 16 + quad * 4;
        float4 vv;
        vv.x = fmaxf(acc[mt][nt][0], 0.f);
        vv.y = fmaxf(acc[mt][nt][1], 0.f);
        vv.z = fmaxf(acc[mt][nt][2], 0.f);
        vv.w = fmaxf(acc[mt][nt][3], 0.f);
        *(float4*)&outf[(size_t)(b * 256 + n) * HW + pos] = vv;
      }
  } else {
    // layers 0-2: ReLU + bf16-hi transposed plane via per-wave LDS slice
    __syncthreads();   // all K-loop s_mem reads done before union reuse
    unsigned short* sW = (unsigned short*)s_mem + wv * 2048;  // [32][64]
#pragma unroll
    for (int mt = 0; mt < 2; ++mt)
#pragma unroll
      for (int nt = 0; nt < 4; ++nt)
#pragma unroll
        for (int r = 0; r < 4; ++r)
          sW[(mt * 16 + quad * 4 + r) * 64 + nt * 16 + frow] =
              (unsigned short)f2bf_bits(fmaxf(acc[mt][nt][r], 0.f));
    __syncthreads();
    const int lm = lane & 31, cg2 = lane >> 5;
    const int pos = h * 64 + mw * 32 + lm;
    unsigned short* __restrict__ yp =
        yth + ((size_t)b * HW + pos) * 256 + nh * 128 + nw * 64 + cg2 * 32;
#pragma unroll
    for (int g = 0; g < 4; ++g)
      *(u16x8*)(yp + g * 8) = *(const u16x8*)&sW[lm * 64 + cg2 * 32 + g * 8];
  }
}

extern "C" void kernel_launch(void* const* d_in, const int* in_sizes, int n_in,
                              void* d_out, int out_size, void* d_ws, size_t ws_size,
                              hipStream_t stream) {
  const float* x0   = (const float*)d_in[0];  // [4][256][64][64]
  const float* offw = (const float*)d_in[1];  // [4][18][256][3][3]
  const float* offb = (const float*)d_in[2];  // [4][18]
  const float* w    = (const float*)d_in[3];  // [4][256][256][3][3]
  float* out = (float*)d_out;                 // [4][256][64][64]
  float* ws  = (float*)d_ws;

  float* offs = ws;                                     //   294,912 floats
  unsigned short* wph  = (unsigned short*)(ws + 294912);    // 2,359,296 ushort
  unsigned short* owph = wph + 2359296;                     //   294,912 ushort
  unsigned short* xTA  = owph + 294912;                     // 4,194,304 ushort
  unsigned short* xTB  = xTA + 4194304;                     // 4,194,304 ushort

  wpack_kernel<<<9216, 256, 0, stream>>>(w, wph);
  offwpack_kernel<<<1152, 256, 0, stream>>>(offw, owph);
  xpose_kernel<<<dim3(64, 4, 4), 256, 0, stream>>>(x0, xTA);

  unsigned short* pin = xTA;
  unsigned short* pout = xTB;
  for (int r = 0; r < 4; ++r) {
    offconv_mfma<<<512, 256, 0, stream>>>(pin, owph + r * 73728,
                                          offb + r * 18, offs);
    deform_mfma<<<512, 256, 0, stream>>>(pin, offs,
                                         wph + (size_t)r * 589824,
                                         (r < 3) ? pout : nullptr,
                                         (r < 3) ? nullptr : out);
    unsigned short* tmp = pin; pin = pout; pout = tmp;
  }
}

// Round 8
// 553.762 us; speedup vs baseline: 1.3891x; 1.3891x over previous
//
#include <hip/hip_runtime.h>

// RepetHead: 4 layers of (3x3 offset conv -> DCNv1 deform conv -> ReLU)
// B=4, C=256, H=W=64, K=9 taps.
// Round 8: barrier-free deform K-loop (r7) fixed per post-mortem:
//  - waves partition M (16 rows each) and span full N=128 -> each lane
//    gathers only its OWN 4 bilinear corners (r7 needed 8: mw-duplication),
//  - explicit register double-buffer with LITERAL indices (r6-proven idiom):
//    chunk cc+1's 4 gathers + 8 B-frags are issued while chunk cc's
//    combine+MFMA run; tap params reload AFTER the dependent combine.
//
// ws layout (floats):
//   offs :   294,912
//   wph  : 1,179,648  (2,359,296 ushort, deform B frag-packed, bf16-hi)
//   owph :   147,456  (  294,912 ushort, offset-conv B frag-packed)
//   xTA  : 2,097,152  (4,194,304 ushort, plane ping)
//   xTB  : 2,097,152  (4,194,304 ushort, plane pong)
// total 5,816,320 floats = 23.3 MB

#define HW 4096

typedef __attribute__((ext_vector_type(8))) __bf16 bf16x8;
typedef __attribute__((ext_vector_type(2))) __bf16 bf16x2;
typedef __attribute__((ext_vector_type(4))) float f32x4;
typedef __attribute__((ext_vector_type(8))) unsigned short u16x8;

__device__ inline unsigned int f2bf_bits(float f) {
  unsigned int u = __float_as_uint(f);
  return (u + 0x7fffu + ((u >> 16) & 1u)) >> 16;   // RNE to bf16
}
__device__ inline float bf_hi_f(unsigned short h) {
  return __uint_as_float(((unsigned int)h) << 16);
}

// split two fp32 into packed bf16 hi words + packed bf16 lo (residual) words
__device__ inline void split2(float v0, float v1,
                              unsigned int& hw, unsigned int& lw) {
#if __has_builtin(__builtin_amdgcn_cvt_pk_bf16_f32)
  bf16x2 h2 = __builtin_amdgcn_cvt_pk_bf16_f32(v0, v1);
  hw = __builtin_bit_cast(unsigned int, h2);
  const float r0 = v0 - __uint_as_float(hw << 16);
  const float r1 = v1 - __uint_as_float(hw & 0xffff0000u);
  bf16x2 l2 = __builtin_amdgcn_cvt_pk_bf16_f32(r0, r1);
  lw = __builtin_bit_cast(unsigned int, l2);
#else
  const unsigned int h0 = f2bf_bits(v0), h1 = f2bf_bits(v1);
  hw = h0 | (h1 << 16);
  const float r0 = v0 - __uint_as_float(h0 << 16);
  const float r1 = v1 - __uint_as_float(h1 << 16);
  lw = f2bf_bits(r0) | (f2bf_bits(r1) << 16);
#endif
}

// ---------------------------------------------------------------------------
// w[r][o][c][ky][kx] -> frag-packed wph[r][q=72][nt=16][lane=64][j=8] (bf16-hi)
// n = nt*16+(lane&15); kk = q*32+(lane>>4)*8+j; c = kk&255; k = kk>>8.
__global__ __launch_bounds__(256) void wpack_kernel(
    const float* __restrict__ w, unsigned short* __restrict__ wph) {
  const int f = blockIdx.x * 256 + threadIdx.x;   // < 2,359,296
  const int j  = f & 7;
  const int l  = (f >> 3) & 63;
  const int nt = (f >> 9) & 15;
  const int q  = (f >> 13) % 72;
  const int r  = f / 589824;
  const int n  = nt * 16 + (l & 15);
  const int kk = q * 32 + ((l >> 4) << 3) + j;
  const int c  = kk & 255, k = kk >> 8;
  wph[f] = (unsigned short)f2bf_bits(w[((r * 256 + n) * 256 + c) * 9 + k]);
}

// offw[r][18][256][3][3] -> owph[r][q=72][nt=2][lane=64][j=8] (n>=18 -> 0)
__global__ __launch_bounds__(256) void offwpack_kernel(
    const float* __restrict__ offw, unsigned short* __restrict__ owph) {
  const int f = blockIdx.x * 256 + threadIdx.x;   // < 294,912
  const int j  = f & 7;
  const int l  = (f >> 3) & 63;
  const int nt = (f >> 9) & 1;
  const int q  = (f >> 10) % 72;
  const int r  = f / 73728;
  const int n  = nt * 16 + (l & 15);
  const int kk = q * 32 + ((l >> 4) << 3) + j;
  const int c  = kk & 255, k = kk >> 8;
  const float v = (n < 18) ? offw[((r * 18 + n) * 256 + c) * 9 + k] : 0.f;
  owph[f] = (unsigned short)f2bf_bits(v);
}

// ---------------------------------------------------------------------------
// x [4][256][4096] fp32 -> xT [4][4096][256] bf16-hi (transpose + cast)
__global__ __launch_bounds__(256) void xpose_kernel(
    const float* __restrict__ x, unsigned short* __restrict__ xh) {
  const int p0 = blockIdx.x * 64;     // pos tile
  const int c0 = blockIdx.y * 64;     // channel tile
  const int b  = blockIdx.z;
  __shared__ float sT[64][65];
  const int t = threadIdx.x;
  const int pj = t & 63, ci0 = (t >> 6) * 16;
  const float* __restrict__ xb = x + ((size_t)(b * 256 + c0)) * HW + p0;
#pragma unroll
  for (int u = 0; u < 16; ++u)
    sT[ci0 + u][pj] = xb[(size_t)(ci0 + u) * HW + pj];
  __syncthreads();
  const int pr = t >> 2, cs = (t & 3) * 16;
  u16x8 va, vb;
#pragma unroll
  for (int u = 0; u < 8; ++u) va[u] = (unsigned short)f2bf_bits(sT[cs + u][pr]);
#pragma unroll
  for (int u = 0; u < 8; ++u) vb[u] = (unsigned short)f2bf_bits(sT[cs + 8 + u][pr]);
  const size_t o = ((size_t)b * HW + p0 + pr) * 256 + c0 + cs;
  *(u16x8*)(xh + o) = va;
  *(u16x8*)(xh + o + 8) = vb;
}

// ---------------------------------------------------------------------------
// Offset conv, zero-LDS MFMA (r4-proven). block = 32m x 32n, 4 waves.
__global__ __launch_bounds__(256) void offconv_mfma(
    const unsigned short* __restrict__ xh,
    const unsigned short* __restrict__ owh,
    const float* __restrict__ bias, float* __restrict__ offs) {
  const int gid = blockIdx.x;                 // 0..511
  const int b = (gid & 7) >> 1;
  const int idx = ((gid >> 3) << 1) | (gid & 1);   // 0..127
  const int h = idx >> 1, w0 = (idx & 1) << 5;
  const int t = threadIdx.x, lane = t & 63, wv = t >> 6;
  const int frow = lane & 15, fgrp = lane >> 4;
  const int mt = wv & 1, nt = wv >> 1;
  const int m = w0 + mt * 16 + frow;          // w coordinate of A row

  f32x4 acc = {0.f, 0.f, 0.f, 0.f};
  const u16x8 z8 = {};
  const size_t xb = (size_t)b * HW;

  for (int k = 0; k < 9; ++k) {
    const int ky = k / 3 - 1, kx = k % 3 - 1;
    if ((unsigned)(h + ky) >= 64u) continue;  // block-uniform: tap row is 0
    const bool vpx = (unsigned)(m + kx) < 64u;
    const int cpx = (m + kx) < 0 ? 0 : ((m + kx) > 63 ? 63 : (m + kx));
    const size_t abase = (xb + (size_t)((h + ky) * 64 + cpx)) * 256 + fgrp * 8;
#pragma unroll
    for (int cc = 0; cc < 8; ++cc) {
      const int q = k * 8 + cc;
      u16x8 ahr = *(const u16x8*)(xh + abase + cc * 32);
      if (!vpx) ahr = z8;
      const u16x8 bhr = ((const u16x8*)owh)[(q * 2 + nt) * 64 + lane];
      const bf16x8 ah = __builtin_bit_cast(bf16x8, ahr);
      const bf16x8 bh = __builtin_bit_cast(bf16x8, bhr);
      acc = __builtin_amdgcn_mfma_f32_16x16x32_bf16(ah, bh, acc, 0, 0, 0);
    }
  }
  const int oc = nt * 16 + frow;              // C/D: col = lane&15 -> n
  if (oc < 18) {
    const float bv = bias[oc];
    const int wbase = w0 + mt * 16 + fgrp * 4;  // C/D: row = (lane>>4)*4 + r
    float* __restrict__ op = offs + (size_t)(b * 18 + oc) * HW + h * 64 + wbase;
#pragma unroll
    for (int r = 0; r < 4; ++r) op[r] = acc[r] + bv;
  }
}

// ---------------------------------------------------------------------------
// Fused bilinear-sample + bf16 MFMA GEMM + ReLU. Register-resident A frags,
// no barriers in the K-loop, explicit double-buffered prefetch.
// Block: M=64 x N=128. Wave wv owns m rows wv*16..wv*16+15, spans all N=128:
// per chunk 8 n-tiles x 2 products (a_hi, a_lo) * b_hi = 16 MFMA.
__global__ __launch_bounds__(256) void deform_mfma(
    const unsigned short* __restrict__ xh,   // [4][4096][256] bf16-hi plane
    const float* __restrict__ offs,          // [4][18][4096]
    const unsigned short* __restrict__ wph,  // [72][16][64][8] this layer
    unsigned short* __restrict__ yth,        // next plane (layers 0-2)
    float* __restrict__ outf) {              // fp32 NCHW out (layer 3)
  const int gid = blockIdx.x;                  // 0..511
  const int b = (gid & 7) >> 1;                // 2 XCDs per batch image
  const int rh = ((gid >> 3) << 1) | (gid & 1);   // 0..127
  const int h = rh >> 1, nh = rh & 1;
  const int t = threadIdx.x, lane = t & 63, wv = t >> 6;
  const int frow = lane & 15, quad = lane >> 4;

  __shared__ __align__(16) unsigned char s_mem[18432];
  float4* s_cw = (float4*)s_mem;               // [9][64] corner weights
  int4*   s_ci = (int4*)(s_mem + 9216);        // [9][64] corner row indices

  // phase 0: per (k, m) bilinear setup, m = w coordinate (full row)
  for (int i = t; i < 576; i += 256) {
    const int k = i >> 6, m = i & 63;
    const int ky = k / 3 - 1, kx = k % 3 - 1;
    const int pos = h * 64 + m;
    const float dy = offs[(b * 18 + 2 * k) * HW + pos];
    const float dx = offs[(b * 18 + 2 * k + 1) * HW + pos];
    const float py = (float)(h + ky) + dy;
    const float px = (float)(m + kx) + dx;
    const float y0f = floorf(py), x0f = floorf(px);
    const float wy = py - y0f, wx = px - x0f;
    const int y0 = (int)y0f, x0 = (int)x0f;
    float cw[4]; int ci[4];
#pragma unroll
    for (int j = 0; j < 4; ++j) {
      const int yi = y0 + (j >> 1), xi = x0 + (j & 1);
      const bool v = (yi >= 0) && (yi < 64) && (xi >= 0) && (xi < 64);
      const float wgt = ((j >> 1) ? wy : 1.f - wy) * ((j & 1) ? wx : 1.f - wx);
      cw[j] = v ? wgt : 0.f;
      const int yc = yi < 0 ? 0 : (yi > 63 ? 63 : yi);
      const int xc = xi < 0 ? 0 : (xi > 63 ? 63 : xi);
      ci[j] = yc * 64 + xc;
    }
    s_cw[k * 64 + m] = (float4){cw[0], cw[1], cw[2], cw[3]};
    s_ci[k * 64 + m] = (int4){ci[0], ci[1], ci[2], ci[3]};
  }
  __syncthreads();

  f32x4 acc[8];
#pragma unroll
  for (int nt = 0; nt < 8; ++nt) acc[nt] = (f32x4){0.f, 0.f, 0.f, 0.f};

  const unsigned short* __restrict__ xbh = xh + (size_t)b * HW * 256;
  const u16x8* __restrict__ wp = (const u16x8*)wph;
  const int nh8 = nh * 8;                      // B frag n-offset
  const int q8 = quad * 8;                     // lane's channel sub-slot
  const int bm = wv * 16 + frow;               // lane's A row (m coordinate)

  float4 cwr;
  const unsigned short *p0, *p1, *p2, *p3;

#define LOAD_TAP(kk)                                                        \
  {                                                                         \
    cwr = s_cw[(kk) * 64 + bm];                                             \
    const int4 ci = s_ci[(kk) * 64 + bm];                                   \
    p0 = xbh + (size_t)ci.x * 256 + q8;                                     \
    p1 = xbh + (size_t)ci.y * 256 + q8;                                     \
    p2 = xbh + (size_t)ci.z * 256 + q8;                                     \
    p3 = xbh + (size_t)ci.w * 256 + q8;                                     \
  }

#define PREFETCH(G, Bf, ccn)                                                \
  {                                                                         \
    const int co = ((ccn) & 7) * 32;                                        \
    G[0] = *(const u16x8*)(p0 + co);                                        \
    G[1] = *(const u16x8*)(p1 + co);                                        \
    G[2] = *(const u16x8*)(p2 + co);                                        \
    G[3] = *(const u16x8*)(p3 + co);                                        \
    _Pragma("unroll") for (int nt = 0; nt < 8; ++nt)                        \
        Bf[nt] = wp[((size_t)(ccn) * 16 + nh8 + nt) * 64 + lane];           \
  }

#define COMBINE(G, AH, AL)                                                  \
  {                                                                         \
    float v[8];                                                             \
    _Pragma("unroll") for (int u = 0; u < 8; ++u) {                         \
      float s = cwr.x * bf_hi_f(G[0][u]);                                   \
      s = fmaf(cwr.y, bf_hi_f(G[1][u]), s);                                 \
      s = fmaf(cwr.z, bf_hi_f(G[2][u]), s);                                 \
      v[u] = fmaf(cwr.w, bf_hi_f(G[3][u]), s);                              \
    }                                                                       \
    uint4 hw4, lw4;                                                         \
    split2(v[0], v[1], hw4.x, lw4.x);                                       \
    split2(v[2], v[3], hw4.y, lw4.y);                                       \
    split2(v[4], v[5], hw4.z, lw4.z);                                       \
    split2(v[6], v[7], hw4.w, lw4.w);                                       \
    AH = __builtin_bit_cast(bf16x8, hw4);                                   \
    AL = __builtin_bit_cast(bf16x8, lw4);                                   \
  }

#define MFMA8(AH, AL, Bf)                                                   \
  {                                                                         \
    _Pragma("unroll") for (int nt = 0; nt < 8; ++nt) {                      \
      const bf16x8 bv = __builtin_bit_cast(bf16x8, Bf[nt]);                 \
      acc[nt] = __builtin_amdgcn_mfma_f32_16x16x32_bf16(AH, bv, acc[nt], 0, 0, 0); \
      acc[nt] = __builtin_amdgcn_mfma_f32_16x16x32_bf16(AL, bv, acc[nt], 0, 0, 0); \
    }                                                                       \
  }

  u16x8 G0[4], G1[4], B0f[8], B1f[8];
  LOAD_TAP(0)
  PREFETCH(G0, B0f, 0)

  for (int it = 0; it < 36; ++it) {
    const int cc0 = it * 2;
    bf16x8 ah, al;
    // chunk cc0: combine (uses tap(cc0) params) -> prefetch cc0+1 -> MFMA
    COMBINE(G0, ah, al)
    PREFETCH(G1, B1f, cc0 + 1)           // cc0+1 odd: same tap, ptrs valid
    MFMA8(ah, al, B0f)
    // chunk cc0+1: combine BEFORE tap reload (cwr still tap(cc0+1))
    COMBINE(G1, ah, al)
    if (it < 35) {
      const int cc2 = cc0 + 2;
      if ((cc2 & 7) == 0) LOAD_TAP(cc2 >> 3)   // tap boundary (even cc only)
      PREFETCH(G0, B0f, cc2)
    }
    MFMA8(ah, al, B1f)
  }
#undef LOAD_TAP
#undef PREFETCH
#undef COMBINE
#undef MFMA8

  if (outf) {
    // final layer: ReLU + direct fp32 NCHW scatter (float4 per n-tile)
#pragma unroll
    for (int nt = 0; nt < 8; ++nt) {
      const int n = nh * 128 + nt * 16 + frow;       // C/D col -> n
      const int pos = h * 64 + wv * 16 + quad * 4;   // C/D row -> m
      float4 vv;
      vv.x = fmaxf(acc[nt][0], 0.f);
      vv.y = fmaxf(acc[nt][1], 0.f);
      vv.z = fmaxf(acc[nt][2], 0.f);
      vv.w = fmaxf(acc[nt][3], 0.f);
      *(float4*)&outf[(size_t)(b * 256 + n) * HW + pos] = vv;
    }
  } else {
    // layers 0-2: ReLU + bf16-hi transposed plane via per-wave LDS slice
    __syncthreads();   // all K-loop s_cw/s_ci reads done before reuse
    unsigned short* sW = (unsigned short*)s_mem + wv * 2048;  // [16][128]
#pragma unroll
    for (int nt = 0; nt < 8; ++nt)
#pragma unroll
      for (int r = 0; r < 4; ++r)
        sW[(quad * 4 + r) * 128 + nt * 16 + frow] =
            (unsigned short)f2bf_bits(fmaxf(acc[nt][r], 0.f));
    __syncthreads();
    const int lm = lane >> 2, cgr = (lane & 3) * 32;
    unsigned short* __restrict__ yp =
        yth + ((size_t)b * HW + h * 64 + wv * 16 + lm) * 256 + nh * 128 + cgr;
#pragma unroll
    for (int g = 0; g < 4; ++g)
      *(u16x8*)(yp + g * 8) = *(const u16x8*)&sW[lm * 128 + cgr + g * 8];
  }
}

extern "C" void kernel_launch(void* const* d_in, const int* in_sizes, int n_in,
                              void* d_out, int out_size, void* d_ws, size_t ws_size,
                              hipStream_t stream) {
  const float* x0   = (const float*)d_in[0];  // [4][256][64][64]
  const float* offw = (const float*)d_in[1];  // [4][18][256][3][3]
  const float* offb = (const float*)d_in[2];  // [4][18]
  const float* w    = (const float*)d_in[3];  // [4][256][256][3][3]
  float* out = (float*)d_out;                 // [4][256][64][64]
  float* ws  = (float*)d_ws;

  float* offs = ws;                                     //   294,912 floats
  unsigned short* wph  = (unsigned short*)(ws + 294912);    // 2,359,296 ushort
  unsigned short* owph = wph + 2359296;                     //   294,912 ushort
  unsigned short* xTA  = owph + 294912;                     // 4,194,304 ushort
  unsigned short* xTB  = xTA + 4194304;                     // 4,194,304 ushort

  wpack_kernel<<<9216, 256, 0, stream>>>(w, wph);
  offwpack_kernel<<<1152, 256, 0, stream>>>(offw, owph);
  xpose_kernel<<<dim3(64, 4, 4), 256, 0, stream>>>(x0, xTA);

  unsigned short* pin = xTA;
  unsigned short* pout = xTB;
  for (int r = 0; r < 4; ++r) {
    offconv_mfma<<<512, 256, 0, stream>>>(pin, owph + r * 73728,
                                          offb + r * 18, offs);
    deform_mfma<<<512, 256, 0, stream>>>(pin, offs,
                                         wph + (size_t)r * 589824,
                                         (r < 3) ? pout : nullptr,
                                         (r < 3) ? nullptr : out);
    unsigned short* tmp = pin; pin = pout; pout = tmp;
  }
}